// Round 4
// baseline (616.273 us; speedup 1.0000x reference)
//
#include <hip/hip_runtime.h>

#define NCH 32

typedef __attribute__((ext_vector_type(8))) __bf16 bf16x8;
typedef __attribute__((ext_vector_type(4))) float  f32x4;

// Split 8 fp32 values into bf16 hi + bf16 lo (residual) fragments.
// ah*bh + al*bh + ah*bl reconstructs the fp32 product to ~2^-16 relative.
static __device__ __forceinline__ void split8(const float* x, bf16x8& hi, bf16x8& lo)
{
#pragma unroll
    for (int e = 0; e < 8; ++e) {
        __bf16 h = (__bf16)x[e];
        hi[e] = h;
        lo[e] = (__bf16)(x[e] - (float)h);
    }
}

static __device__ __forceinline__ void mfma3(
    const bf16x8& ah, const bf16x8& al,
    const bf16x8& wh, const bf16x8& wl, f32x4& acc)
{
    acc = __builtin_amdgcn_mfma_f32_16x16x32_bf16(ah, wh, acc, 0, 0, 0);
    acc = __builtin_amdgcn_mfma_f32_16x16x32_bf16(al, wh, acc, 0, 0, 0);
    acc = __builtin_amdgcn_mfma_f32_16x16x32_bf16(ah, wl, acc, 0, 0, 0);
}

// ---------------------------------------------------------------------------
// Weight composition: Weff[a][b][c] = W1[c] @ W2[b] @ W3[a]  (fp32, 32x32),
// packed in MFMA B-fragment order as bf16 hi/lo:
//   wfrag[((m*2 + h)*2 + part)*64 + lane][e] = part==0 ? hi : lo of
//       Weff[m][(lane>>4)*8 + e][h*16 + (lane&15)]
// One block per combo m = a*9 + b*3 + c. Block 0 also zeroes stats[64].
// ---------------------------------------------------------------------------
__global__ __launch_bounds__(256) void weight_prep_kernel(
    const float* __restrict__ W1, const float* __restrict__ W2,
    const float* __restrict__ W3, __bf16* __restrict__ wfrag,
    float* __restrict__ stats)
{
    const int m = blockIdx.x;          // 0..26
    const int a = m / 9;
    const int b = (m % 9) / 3;
    const int c = m % 3;

    __shared__ float T[32][33];
    __shared__ float E[32][33];

    const float* Wc = W1 + c * NCH * NCH;   // [Cin][mid1]
    const float* Wb = W2 + b * NCH * NCH;   // [mid1][mid2]
    const float* Wa = W3 + a * NCH * NCH;   // [mid2][Cout]

    for (int e = threadIdx.x; e < NCH * NCH; e += 256) {
        int i = e >> 5, j = e & 31;
        float acc = 0.f;
        for (int u = 0; u < NCH; ++u)
            acc = fmaf(Wc[i * NCH + u], Wb[u * NCH + j], acc);
        T[i][j] = acc;
    }
    __syncthreads();
    for (int e = threadIdx.x; e < NCH * NCH; e += 256) {
        int i = e >> 5, j = e & 31;
        float acc = 0.f;
        for (int u = 0; u < NCH; ++u)
            acc = fmaf(T[i][u], Wa[u * NCH + j], acc);
        E[i][j] = acc;
    }
    __syncthreads();

    if (threadIdx.x < 64) {
        int lane = threadIdx.x, r16 = lane & 15, c0 = (lane >> 4) * 8;
        for (int h = 0; h < 2; ++h) {
            __bf16* dhi = wfrag + ((((size_t)m * 2 + h) * 2 + 0) * 64 + lane) * 8;
            __bf16* dlo = wfrag + ((((size_t)m * 2 + h) * 2 + 1) * 64 + lane) * 8;
            for (int e = 0; e < 8; ++e) {
                float v = E[c0 + e][h * 16 + r16];
                __bf16 hv = (__bf16)v;
                dhi[e] = hv;
                dlo[e] = (__bf16)(v - (float)hv);
            }
        }
    }
    if (m == 0 && threadIdx.x < 64) stats[threadIdx.x] = 0.f;
}

static __device__ __forceinline__ void load_wfrag(
    const __bf16* __restrict__ wfrag, int m, int lane,
    bf16x8& h0, bf16x8& l0, bf16x8& h1, bf16x8& l1)
{
    const bf16x8* base = (const bf16x8*)wfrag;
    h0 = base[((m * 2 + 0) * 2 + 0) * 64 + lane];
    l0 = base[((m * 2 + 0) * 2 + 1) * 64 + lane];
    h1 = base[((m * 2 + 1) * 2 + 0) * 64 + lane];
    l1 = base[((m * 2 + 1) * 2 + 1) * 64 + lane];
}

// ---------------------------------------------------------------------------
// Fully fused 3x3x3 sparse conv via composed path weights.
// h3[p] = sum over paths p -x-> q -y-> r -z-> s of f[s] @ Weff[a][b][c];
// a path contributes only if every intermediate voxel is active (idx < n),
// exactly matching three chained 1-D convs. Tap 1 of each axis is the
// identity map (verified structure), so its index load is skipped.
// Index levels are loaded breadth-first (clamped, unconditional); the 27
// leaf combos run center-first, each behind a wave-uniform __any skip
// (expected ~5.5 of 27 active at 6% voxel occupancy).
// A fragment: lane holds f[tb + (lane&15)][c0..c0+7], invalid paths zeroed.
// C/D: out[tb + (lane>>4)*4 + r][(lane&15) + 16*half].
// BN per-channel sum/sumsq fused in the epilogue.
// ---------------------------------------------------------------------------
__global__ __launch_bounds__(256) void conv_fused_kernel(
    const float* __restrict__ f, const int* __restrict__ nbr,
    const __bf16* __restrict__ wfrag, float* __restrict__ out, int n,
    float* __restrict__ stats)
{
    __shared__ float red[4][4][16];

    const int lane = threadIdx.x & 63;
    const int wv   = threadIdx.x >> 6;
    const int r16  = lane & 15;
    const int g    = lane >> 4;
    const int c0   = g * 8;

    const int ntiles = (n + 15) >> 4;
    const int tile   = blockIdx.x * 4 + wv;

    float s0 = 0.f, q0s = 0.f, s1 = 0.f, q1s = 0.f;

    if (tile < ntiles) {
        const int  tb  = tile << 4;
        const int  p   = tb + r16;
        const bool pin = (p < n);
        const int  pc  = pin ? p : (n - 1);

        const int* nbr0m = nbr;                    // axis 0 (x), tap -1
        const int* nbr0p = nbr + 2 * (size_t)n;    // axis 0, tap +1
        const int* nbr1m = nbr + 3 * (size_t)n;    // axis 1 (y)
        const int* nbr1p = nbr + 5 * (size_t)n;
        const int* nbr2m = nbr + 6 * (size_t)n;    // axis 2 (z)
        const int* nbr2p = nbr + 8 * (size_t)n;

        // ---- level A: q = x-neighbors of p ----
        int qv[3]; bool qm[3];
        qv[1] = pc; qm[1] = pin;
        {
            int t0 = nbr0m[pc], t2 = nbr0p[pc];
            qm[0] = pin && t0 < n; qv[0] = qm[0] ? t0 : 0;
            qm[2] = pin && t2 < n; qv[2] = qm[2] ? t2 : 0;
        }

        // ---- level B: r = y-neighbors of q ----
        int rv[3][3]; bool rm[3][3];
#pragma unroll
        for (int a = 0; a < 3; ++a) {
            rv[a][1] = qv[a]; rm[a][1] = qm[a];
            int t0 = nbr1m[qv[a]], t2 = nbr1p[qv[a]];
            rm[a][0] = qm[a] && t0 < n; rv[a][0] = rm[a][0] ? t0 : 0;
            rm[a][2] = qm[a] && t2 < n; rv[a][2] = rm[a][2] ? t2 : 0;
        }

        // ---- level C: s = z-neighbors of r (store only c=0,2; c=1 == r) ----
        int sv[3][3][2]; bool sm[3][3][2];
#pragma unroll
        for (int a = 0; a < 3; ++a)
#pragma unroll
            for (int b = 0; b < 3; ++b) {
                int t0 = nbr2m[rv[a][b]], t2 = nbr2p[rv[a][b]];
                sm[a][b][0] = rm[a][b] && t0 < n; sv[a][b][0] = sm[a][b][0] ? t0 : 0;
                sm[a][b][1] = rm[a][b] && t2 < n; sv[a][b][1] = sm[a][b][1] ? t2 : 0;
            }

        f32x4 acc0 = {0.f, 0.f, 0.f, 0.f};
        f32x4 acc1 = {0.f, 0.f, 0.f, 0.f};

        auto leaf = [&](int m, int sidx, bool v) {
            if (__any(v)) {
                const float4* rp =
                    (const float4*)(f + (size_t)(v ? sidx : 0) * NCH + c0);
                float4 x0 = rp[0], x1 = rp[1];
                float mm = v ? 1.f : 0.f;
                float xx[8] = {x0.x * mm, x0.y * mm, x0.z * mm, x0.w * mm,
                               x1.x * mm, x1.y * mm, x1.z * mm, x1.w * mm};
                bf16x8 ah, al, wh0, wl0, wh1, wl1;
                split8(xx, ah, al);
                load_wfrag(wfrag, m, lane, wh0, wl0, wh1, wl1);
                mfma3(ah, al, wh0, wl0, acc0);
                mfma3(ah, al, wh1, wl1, acc1);
            }
        };

        const int ord[3] = {1, 0, 2};   // center-first at every level
#pragma unroll
        for (int ia = 0; ia < 3; ++ia)
#pragma unroll
            for (int ib = 0; ib < 3; ++ib)
#pragma unroll
                for (int ic = 0; ic < 3; ++ic) {
                    const int a = ord[ia], b = ord[ib], cc = ord[ic];
                    const int m = a * 9 + b * 3 + cc;
                    if (cc == 1) leaf(m, rv[a][b], rm[a][b]);
                    else         leaf(m, sv[a][b][cc >> 1], sm[a][b][cc >> 1]);
                }

        // ---- store C ----
#pragma unroll
        for (int r = 0; r < 4; ++r) {
            int prow = tb + g * 4 + r;
            if (prow < n) {
                float* o = out + (size_t)prow * NCH + r16;
                o[0]  = acc0[r];
                o[16] = acc1[r];
            }
        }

        // ---- fused BN partial stats ----
#pragma unroll
        for (int r = 0; r < 4; ++r) {
            s0 += acc0[r]; q0s = fmaf(acc0[r], acc0[r], q0s);
            s1 += acc1[r]; q1s = fmaf(acc1[r], acc1[r], q1s);
        }
    }

    // lanes with the same (lane&15) hold the same channel: xor-16/32 reduce
    s0  += __shfl_xor(s0, 16);  s0  += __shfl_xor(s0, 32);
    q0s += __shfl_xor(q0s, 16); q0s += __shfl_xor(q0s, 32);
    s1  += __shfl_xor(s1, 16);  s1  += __shfl_xor(s1, 32);
    q1s += __shfl_xor(q1s, 16); q1s += __shfl_xor(q1s, 32);
    if (lane < 16) {
        red[wv][0][r16] = s0;
        red[wv][1][r16] = q0s;
        red[wv][2][r16] = s1;
        red[wv][3][r16] = q1s;
    }
    __syncthreads();
    if (threadIdx.x < 64) {
        int vsel = threadIdx.x >> 4;   // 0:sum lo, 1:sq lo, 2:sum hi, 3:sq hi
        int ch   = threadIdx.x & 15;
        float t = red[0][vsel][ch] + red[1][vsel][ch] +
                  red[2][vsel][ch] + red[3][vsel][ch];
        int channel = (vsel & 2) ? (ch + 16) : ch;
        atomicAdd(stats + ((vsel & 1) ? NCH : 0) + channel, t);
    }
}

// BatchNorm (batch stats) + ReLU, in place on h [n,32]. One float4 per thread.
__global__ __launch_bounds__(256) void bn_relu_kernel(
    float* h, const float* __restrict__ stats,
    const float* __restrict__ gamma, const float* __restrict__ beta, int n)
{
    long tid = (long)blockIdx.x * 256 + threadIdx.x;
    long total4 = (long)n * NCH / 4;
    if (tid >= total4) return;

    int ch0 = ((int)(tid & 7)) * 4;
    float inv_n = 1.f / (float)n;

    float4 v = ((const float4*)h)[tid];
    float r[4] = {v.x, v.y, v.z, v.w};
#pragma unroll
    for (int j = 0; j < 4; ++j) {
        int ch = ch0 + j;
        float mean = stats[ch] * inv_n;
        float var = stats[NCH + ch] * inv_n - mean * mean;
        float scale = gamma[ch] * rsqrtf(var + 1e-5f);
        float shift = beta[ch] - mean * scale;
        float o = fmaf(r[j], scale, shift);
        r[j] = o > 0.f ? o : 0.f;
    }
    float4 o4;
    o4.x = r[0]; o4.y = r[1]; o4.z = r[2]; o4.w = r[3];
    ((float4*)h)[tid] = o4;
}

extern "C" void kernel_launch(void* const* d_in, const int* in_sizes, int n_in,
                              void* d_out, int out_size, void* d_ws, size_t ws_size,
                              hipStream_t stream)
{
    const float* feats = (const float*)d_in[0];
    const float* W1    = (const float*)d_in[1];
    const float* W2    = (const float*)d_in[2];
    const float* W3    = (const float*)d_in[3];
    const float* gamma = (const float*)d_in[4];
    const float* beta  = (const float*)d_in[5];
    const int*   nbr   = (const int*)d_in[6];   // [3 axes][3 taps][n]

    int n = in_sizes[0] / NCH;

    float*  hout  = (float*)d_out;
    __bf16* wfrag = (__bf16*)d_ws;                        // 110,592 B
    float*  stats = (float*)((char*)d_ws + 131072);       // 64 floats

    // compose + pack weights, zero stats (27 blocks, ~µs)
    weight_prep_kernel<<<27, 256, 0, stream>>>(W1, W2, W3, wfrag, stats);

    // single fused conv pass with BN stats
    int ntiles  = (n + 15) >> 4;
    int cblocks = (ntiles + 3) / 4;
    conv_fused_kernel<<<cblocks, 256, 0, stream>>>(feats, nbr, wfrag, hout, n, stats);

    // BN + ReLU in place
    long total4 = (long)n * NCH / 4;
    int nblocks = (int)((total4 + 255) / 256);
    bn_relu_kernel<<<nblocks, 256, 0, stream>>>(hout, stats, gamma, beta, n);
}

// Round 5
// 552.097 us; speedup vs baseline: 1.1162x; 1.1162x over previous
//
#include <hip/hip_runtime.h>

#define NCH 32

typedef __attribute__((ext_vector_type(8))) __bf16 bf16x8;
typedef __attribute__((ext_vector_type(4))) float  f32x4;

// mask-scale 8 fp32 and split into bf16 hi + lo (residual) fragments.
// ah*bh + al*bh + ah*bl reconstructs the fp32 product to ~2^-16 relative.
static __device__ __forceinline__ void split8m(
    const float4& x0, const float4& x1, float m, bf16x8& hi, bf16x8& lo)
{
    float x[8] = {x0.x * m, x0.y * m, x0.z * m, x0.w * m,
                  x1.x * m, x1.y * m, x1.z * m, x1.w * m};
#pragma unroll
    for (int e = 0; e < 8; ++e) {
        __bf16 h = (__bf16)x[e];
        hi[e] = h;
        lo[e] = (__bf16)(x[e] - (float)h);
    }
}

// Factorized 1D sparse conv as MFMA GEMM, 2 tiles (32 points) per wave.
// A fragment: lane holds f[row = tb + (lane&15)][c0..c0+7], c0=(lane>>4)*8.
// B fragments live in LDS (packed bf16 hi/lo at block start) so they cost
// no VGPRs across the computation; freed registers hold TWO tiles' loads
// in flight (own rows + idx + up to 4 conditional gathers) before compute.
// C/D: out[tb + (lane>>4)*4 + r][(lane&15) + 16*half].
// Tap 1 is the identity map (offset 0) -> own row, no index load.
// do_stats: fused per-channel sum/sumsq, block LDS combine, 64 atomics/block.
__global__ __launch_bounds__(256) void conv_mfma_kernel(
    const float* __restrict__ f, const float* __restrict__ W,
    const int* __restrict__ idx, float* __restrict__ out, int n,
    float* __restrict__ stats, int do_stats)
{
    __shared__ bf16x8 wlds[12 * 64];     // [tap][half][part][lane]
    __shared__ float red[4][4][16];

    // cooperative pack: wlds[(tap*4 + h*2 + part)*64 + lane][e] =
    //   part==0 ? hi : lo of W[tap][(lane>>4)*8 + e][h*16 + (lane&15)]
    for (int j = threadIdx.x; j < 12 * 64; j += 256) {
        int lane_ = j & 63;
        int rest  = j >> 6;
        int part  = rest & 1;
        int h     = (rest >> 1) & 1;
        int tap   = rest >> 2;
        int r16_  = lane_ & 15;
        int c0_   = (lane_ >> 4) * 8;
        const float* Wt = W + tap * NCH * NCH;
        bf16x8 v;
#pragma unroll
        for (int e = 0; e < 8; ++e) {
            float x = Wt[(c0_ + e) * NCH + h * 16 + r16_];
            __bf16 hv = (__bf16)x;
            v[e] = (part == 0) ? hv : (__bf16)(x - (float)hv);
        }
        wlds[j] = v;
    }
    __syncthreads();

    const int lane = threadIdx.x & 63;
    const int wv   = threadIdx.x >> 6;
    const int r16  = lane & 15;
    const int g    = lane >> 4;
    const int c0   = g * 8;

    const int ntiles = (n + 15) >> 4;
    const int pair   = blockIdx.x * 4 + wv;
    const int tA     = pair * 2;
    const int tB     = pair * 2 + 1;

    const int  pA  = (tA << 4) + r16;
    const bool inA = (tA < ntiles) && (pA < n);
    const int  pcA = inA ? pA : 0;
    const int  pB  = (tB << 4) + r16;
    const bool inB = (tB < ntiles) && (pB < n);
    const int  pcB = inB ? pB : 0;

    // ---- own rows (streaming, always issued) ----
    const float4* rA = (const float4*)(f + (size_t)pcA * NCH + c0);
    float4 oA0 = rA[0], oA1 = rA[1];
    const float4* rB = (const float4*)(f + (size_t)pcB * NCH + c0);
    float4 oB0 = rB[0], oB1 = rB[1];

    // ---- neighbor indices (coalesced) ----
    int iA0 = idx[pcA], iA2 = idx[2 * (size_t)n + pcA];
    int iB0 = idx[pcB], iB2 = idx[2 * (size_t)n + pcB];
    bool mA0 = inA && (iA0 < n), mA2 = inA && (iA2 < n);
    bool mB0 = inB && (iB0 < n), mB2 = inB && (iB2 < n);
    bool aA0 = __any(mA0), aA2 = __any(mA2);
    bool aB0 = __any(mB0), aB2 = __any(mB2);

    // ---- all conditional gathers issued before any compute ----
    float4 gA00 = {0,0,0,0}, gA01 = {0,0,0,0}, gA20 = {0,0,0,0}, gA21 = {0,0,0,0};
    float4 gB00 = {0,0,0,0}, gB01 = {0,0,0,0}, gB20 = {0,0,0,0}, gB21 = {0,0,0,0};
    if (aA0) { const float4* p = (const float4*)(f + (size_t)(mA0 ? iA0 : 0) * NCH + c0); gA00 = p[0]; gA01 = p[1]; }
    if (aA2) { const float4* p = (const float4*)(f + (size_t)(mA2 ? iA2 : 0) * NCH + c0); gA20 = p[0]; gA21 = p[1]; }
    if (aB0) { const float4* p = (const float4*)(f + (size_t)(mB0 ? iB0 : 0) * NCH + c0); gB00 = p[0]; gB01 = p[1]; }
    if (aB2) { const float4* p = (const float4*)(f + (size_t)(mB2 ? iB2 : 0) * NCH + c0); gB20 = p[0]; gB21 = p[1]; }

    f32x4 cA0 = {0.f,0.f,0.f,0.f}, cA1 = {0.f,0.f,0.f,0.f};
    f32x4 cB0 = {0.f,0.f,0.f,0.f}, cB1 = {0.f,0.f,0.f,0.f};

    auto leaf = [&](int tap, const float4& x0, const float4& x1, bool v, bool anyv,
                    f32x4& A0, f32x4& A1) {
        if (anyv) {
            bf16x8 ah, al;
            split8m(x0, x1, v ? 1.f : 0.f, ah, al);
            bf16x8 wh0 = wlds[(tap * 4 + 0) * 64 + lane];
            bf16x8 wl0 = wlds[(tap * 4 + 1) * 64 + lane];
            A0 = __builtin_amdgcn_mfma_f32_16x16x32_bf16(ah, wh0, A0, 0, 0, 0);
            A0 = __builtin_amdgcn_mfma_f32_16x16x32_bf16(al, wh0, A0, 0, 0, 0);
            A0 = __builtin_amdgcn_mfma_f32_16x16x32_bf16(ah, wl0, A0, 0, 0, 0);
            bf16x8 wh1 = wlds[(tap * 4 + 2) * 64 + lane];
            bf16x8 wl1 = wlds[(tap * 4 + 3) * 64 + lane];
            A1 = __builtin_amdgcn_mfma_f32_16x16x32_bf16(ah, wh1, A1, 0, 0, 0);
            A1 = __builtin_amdgcn_mfma_f32_16x16x32_bf16(al, wh1, A1, 0, 0, 0);
            A1 = __builtin_amdgcn_mfma_f32_16x16x32_bf16(ah, wl1, A1, 0, 0, 0);
        }
    };

    // centers first (own rows arrive first), then gathers (latency overlapped)
    leaf(1, oA0, oA1, inA, __any(inA), cA0, cA1);
    leaf(1, oB0, oB1, inB, __any(inB), cB0, cB1);
    leaf(0, gA00, gA01, mA0, aA0, cA0, cA1);
    leaf(2, gA20, gA21, mA2, aA2, cA0, cA1);
    leaf(0, gB00, gB01, mB0, aB0, cB0, cB1);
    leaf(2, gB20, gB21, mB2, aB2, cB0, cB1);

    // ---- store C: row = tb + g*4 + r, col = r16 / r16+16 ----
#pragma unroll
    for (int r = 0; r < 4; ++r) {
        int prow = (tA << 4) + g * 4 + r;
        if (prow < n) {
            float* o = out + (size_t)prow * NCH + r16;
            o[0]  = cA0[r];
            o[16] = cA1[r];
        }
    }
#pragma unroll
    for (int r = 0; r < 4; ++r) {
        int prow = (tB << 4) + g * 4 + r;
        if (prow < n) {
            float* o = out + (size_t)prow * NCH + r16;
            o[0]  = cB0[r];
            o[16] = cB1[r];
        }
    }

    if (do_stats) {
        float s0 = 0.f, q0 = 0.f, s1 = 0.f, q1 = 0.f;
#pragma unroll
        for (int r = 0; r < 4; ++r) {
            s0 += cA0[r] + cB0[r];
            q0 = fmaf(cA0[r], cA0[r], q0); q0 = fmaf(cB0[r], cB0[r], q0);
            s1 += cA1[r] + cB1[r];
            q1 = fmaf(cA1[r], cA1[r], q1); q1 = fmaf(cB1[r], cB1[r], q1);
        }
        // lanes with the same (lane&15) hold the same channel
        s0 += __shfl_xor(s0, 16); s0 += __shfl_xor(s0, 32);
        q0 += __shfl_xor(q0, 16); q0 += __shfl_xor(q0, 32);
        s1 += __shfl_xor(s1, 16); s1 += __shfl_xor(s1, 32);
        q1 += __shfl_xor(q1, 16); q1 += __shfl_xor(q1, 32);
        if (lane < 16) {
            red[wv][0][r16] = s0;
            red[wv][1][r16] = q0;
            red[wv][2][r16] = s1;
            red[wv][3][r16] = q1;
        }
        __syncthreads();
        if (threadIdx.x < 64) {
            int vsel = threadIdx.x >> 4;   // 0:sum lo, 1:sq lo, 2:sum hi, 3:sq hi
            int ch   = threadIdx.x & 15;
            float t = red[0][vsel][ch] + red[1][vsel][ch] +
                      red[2][vsel][ch] + red[3][vsel][ch];
            int channel = (vsel & 2) ? (ch + 16) : ch;
            atomicAdd(stats + ((vsel & 1) ? NCH : 0) + channel, t);
        }
    }
}

// BatchNorm (batch stats) + ReLU, in place on h [n,32]. One float4 per thread.
__global__ __launch_bounds__(256) void bn_relu_kernel(
    float* h, const float* __restrict__ stats,
    const float* __restrict__ gamma, const float* __restrict__ beta, int n)
{
    long tid = (long)blockIdx.x * 256 + threadIdx.x;
    long total4 = (long)n * NCH / 4;
    if (tid >= total4) return;

    int ch0 = ((int)(tid & 7)) * 4;
    float inv_n = 1.f / (float)n;

    float4 v = ((const float4*)h)[tid];
    float r[4] = {v.x, v.y, v.z, v.w};
#pragma unroll
    for (int j = 0; j < 4; ++j) {
        int ch = ch0 + j;
        float mean = stats[ch] * inv_n;
        float var = stats[NCH + ch] * inv_n - mean * mean;
        float scale = gamma[ch] * rsqrtf(var + 1e-5f);
        float shift = beta[ch] - mean * scale;
        float o = fmaf(r[j], scale, shift);
        r[j] = o > 0.f ? o : 0.f;
    }
    float4 o4;
    o4.x = r[0]; o4.y = r[1]; o4.z = r[2]; o4.w = r[3];
    ((float4*)h)[tid] = o4;
}

extern "C" void kernel_launch(void* const* d_in, const int* in_sizes, int n_in,
                              void* d_out, int out_size, void* d_ws, size_t ws_size,
                              hipStream_t stream)
{
    const float* feats = (const float*)d_in[0];
    const float* W1    = (const float*)d_in[1];
    const float* W2    = (const float*)d_in[2];
    const float* W3    = (const float*)d_in[3];
    const float* gamma = (const float*)d_in[4];
    const float* beta  = (const float*)d_in[5];
    const int*   nbr   = (const int*)d_in[6];   // [3 axes][3 taps][n]

    int n = in_sizes[0] / NCH;

    float* hout  = (float*)d_out;                // h1, then h3, then final out
    float* h2    = (float*)d_ws;                 // n*32 floats
    float* stats = h2 + (size_t)n * NCH;         // 64 floats

    int ntiles  = (n + 15) >> 4;
    int cblocks = (ntiles + 7) / 8;              // 4 waves x 2 tiles per block

    // conv1: axis 2 (z), feats -> d_out
    conv_mfma_kernel<<<cblocks, 256, 0, stream>>>(feats, W1, nbr + (size_t)2 * 3 * n,
                                                  hout, n, nullptr, 0);
    // conv2: axis 1 (y), d_out -> ws
    conv_mfma_kernel<<<cblocks, 256, 0, stream>>>(hout, W2, nbr + (size_t)1 * 3 * n,
                                                  h2, n, nullptr, 0);

    // zero BN accumulators before conv3 (which fuses the stats reduction)
    hipMemsetAsync(stats, 0, 2 * NCH * sizeof(float), stream);

    // conv3: axis 0 (x), ws -> d_out, with fused per-channel sum/sumsq
    conv_mfma_kernel<<<cblocks, 256, 0, stream>>>(h2, W3, nbr + (size_t)0 * 3 * n,
                                                  hout, n, stats, 1);

    // BN + ReLU in place
    long total4 = (long)n * NCH / 4;
    int nblocks = (int)((total4 + 255) / 256);
    bn_relu_kernel<<<nblocks, 256, 0, stream>>>(hout, stats, gamma, beta, n);
}

// Round 7
// 414.689 us; speedup vs baseline: 1.4861x; 1.3314x over previous
//
#include <hip/hip_runtime.h>

#define NCH 32

typedef __attribute__((ext_vector_type(8))) __bf16 bf16x8;
typedef __attribute__((ext_vector_type(4))) float  f32x4;

union bcast16 { int4 i; bf16x8 h; };

// Split 8 fp32 values into bf16 hi + bf16 lo (residual) fragments.
// ah*bh + al*bh + ah*bl reconstructs the fp32 product to ~2^-16 relative.
static __device__ __forceinline__ void split8(const float* x, bf16x8& hi, bf16x8& lo)
{
#pragma unroll
    for (int e = 0; e < 8; ++e) {
        __bf16 h = (__bf16)x[e];
        hi[e] = h;
        lo[e] = (__bf16)(x[e] - (float)h);
    }
}

static __device__ __forceinline__ void mfma3(
    const bf16x8& ah, const bf16x8& al,
    const bf16x8& wh, const bf16x8& wl, f32x4& acc)
{
    acc = __builtin_amdgcn_mfma_f32_16x16x32_bf16(ah, wh, acc, 0, 0, 0);
    acc = __builtin_amdgcn_mfma_f32_16x16x32_bf16(al, wh, acc, 0, 0, 0);
    acc = __builtin_amdgcn_mfma_f32_16x16x32_bf16(ah, wl, acc, 0, 0, 0);
}

static __device__ __forceinline__ ushort f2bf(float x)
{
    __bf16 b = (__bf16)x;
    return *(const ushort*)&b;
}

// Factorized 1D sparse conv as MFMA GEMM over 16-point tiles — round-2
// structure verbatim; in/out dtypes templated.
// IN_BF16:  input rows are bf16 [n][32]; A fragment = one 16B load, no split.
// !IN_BF16: input rows are fp32; A split into bf16 hi/lo (exact to ~2^-16).
// OUT_BF16: store accumulators as bf16 (RNE); else fp32.
// A fragment: lane holds f[row = tb + (lane&15)][c0..c0+7], c0=(lane>>4)*8.
// B fragments (3 taps x 2 halves, hi/lo = fp32-exact weights) in registers.
// C/D: out[tb + (lane>>4)*4 + r][(lane&15) + 16*half].
// Tap 1 is the identity map (offset 0) -> own row, no index load.
// Taps 0/2 behind wave-uniform __any skip (~37% whole-tile skip at 6% occ).
// DO_STATS: fused per-channel sum/sumsq from the fp32 accumulators,
// shuffle+LDS combine, 64 atomicAdds per block.
template<int IN_BF16, int OUT_BF16, int DO_STATS>
__global__ __launch_bounds__(256) void conv_mfma_kernel(
    const void* __restrict__ fin, const float* __restrict__ W,
    const int* __restrict__ idx, void* __restrict__ outv, int n,
    float* __restrict__ stats)
{
    __shared__ float red[4][4][16];

    const int lane = threadIdx.x & 63;
    const int wv   = threadIdx.x >> 6;
    const int r16  = lane & 15;
    const int g    = lane >> 4;
    const int c0   = g * 8;

    const float*  ff = (const float*)fin;
    const ushort* fb = (const ushort*)fin;
    float*  of = (float*)outv;
    ushort* ob = (ushort*)outv;

    // B fragments: 3 taps x 2 output halves, hi/lo split (held in VGPRs).
    bf16x8 bh[3][2], bl[3][2];
#pragma unroll
    for (int k = 0; k < 3; ++k) {
#pragma unroll
        for (int h = 0; h < 2; ++h) {
            float w8[8];
#pragma unroll
            for (int e = 0; e < 8; ++e)
                w8[e] = W[k * NCH * NCH + (c0 + e) * NCH + (h * 16 + r16)];
            split8(w8, bh[k][h], bl[k][h]);
        }
    }

    const int ntiles = (n + 15) >> 4;
    const int nw = gridDim.x * 4;
    float s0 = 0.f, q0 = 0.f, s1 = 0.f, q1 = 0.f;

    for (int tile = blockIdx.x * 4 + wv; tile < ntiles; tile += nw) {
        const int tb = tile << 4;
        f32x4 a0 = {0.f, 0.f, 0.f, 0.f};
        f32x4 a1 = {0.f, 0.f, 0.f, 0.f};

        const int  p   = tb + r16;
        const bool pin = (p < n);

        auto dotap = [&](int k, int row, bool v) {
            if constexpr (IN_BF16) {
                int4 raw = *(const int4*)(fb + (size_t)row * NCH + c0);
                if (!v) { raw.x = 0; raw.y = 0; raw.z = 0; raw.w = 0; }
                bcast16 u; u.i = raw;
                a0 = __builtin_amdgcn_mfma_f32_16x16x32_bf16(u.h, bh[k][0], a0, 0, 0, 0);
                a0 = __builtin_amdgcn_mfma_f32_16x16x32_bf16(u.h, bl[k][0], a0, 0, 0, 0);
                a1 = __builtin_amdgcn_mfma_f32_16x16x32_bf16(u.h, bh[k][1], a1, 0, 0, 0);
                a1 = __builtin_amdgcn_mfma_f32_16x16x32_bf16(u.h, bl[k][1], a1, 0, 0, 0);
            } else {
                const float4* rp = (const float4*)(ff + (size_t)row * NCH + c0);
                float4 x0 = rp[0];
                float4 x1 = rp[1];
                float m = v ? 1.f : 0.f;
                float x[8] = {x0.x * m, x0.y * m, x0.z * m, x0.w * m,
                              x1.x * m, x1.y * m, x1.z * m, x1.w * m};
                bf16x8 ah, al;
                split8(x, ah, al);
                mfma3(ah, al, bh[k][0], bl[k][0], a0);
                mfma3(ah, al, bh[k][1], bl[k][1], a1);
            }
        };

        // ---- tap 1: identity (own row) ----
        dotap(1, pin ? p : 0, pin);

        // ---- taps 0 and 2: random gathers ----
#pragma unroll
        for (int t = 0; t < 2; ++t) {
            const int k = t * 2;
            int  i = idx[(size_t)k * n + (pin ? p : 0)];
            bool v = pin && (i < n);
            if (__any(v)) dotap(k, v ? i : 0, v);
        }

        // ---- store C: row = tb + g*4 + r, col = r16 / r16+16 ----
#pragma unroll
        for (int r = 0; r < 4; ++r) {
            int prow = tb + g * 4 + r;
            if (prow < n) {
                if constexpr (OUT_BF16) {
                    ushort* o = ob + (size_t)prow * NCH + r16;
                    o[0]  = f2bf(a0[r]);
                    o[16] = f2bf(a1[r]);
                } else {
                    float* o = of + (size_t)prow * NCH + r16;
                    o[0]  = a0[r];
                    o[16] = a1[r];
                }
            }
        }

        if constexpr (DO_STATS) {
#pragma unroll
            for (int r = 0; r < 4; ++r) {
                s0 += a0[r]; q0 = fmaf(a0[r], a0[r], q0);
                s1 += a1[r]; q1 = fmaf(a1[r], a1[r], q1);
            }
        }
    }

    if constexpr (DO_STATS) {
        // lanes with the same (lane&15) hold the same channel: xor-16/32 reduce
        s0 += __shfl_xor(s0, 16); s0 += __shfl_xor(s0, 32);
        q0 += __shfl_xor(q0, 16); q0 += __shfl_xor(q0, 32);
        s1 += __shfl_xor(s1, 16); s1 += __shfl_xor(s1, 32);
        q1 += __shfl_xor(q1, 16); q1 += __shfl_xor(q1, 32);
        if (lane < 16) {
            red[wv][0][r16] = s0;
            red[wv][1][r16] = q0;
            red[wv][2][r16] = s1;
            red[wv][3][r16] = q1;
        }
        __syncthreads();
        if (threadIdx.x < 64) {
            int vsel = threadIdx.x >> 4;   // 0:sum lo, 1:sq lo, 2:sum hi, 3:sq hi
            int ch   = threadIdx.x & 15;
            float t = red[0][vsel][ch] + red[1][vsel][ch] +
                      red[2][vsel][ch] + red[3][vsel][ch];
            int channel = (vsel & 2) ? (ch + 16) : ch;
            atomicAdd(stats + ((vsel & 1) ? NCH : 0) + channel, t);
        }
    }
}

// BatchNorm (batch stats) + ReLU, in place on h [n,32]. One float4 per thread.
__global__ __launch_bounds__(256) void bn_relu_kernel(
    float* h, const float* __restrict__ stats,
    const float* __restrict__ gamma, const float* __restrict__ beta, int n)
{
    long tid = (long)blockIdx.x * 256 + threadIdx.x;
    long total4 = (long)n * NCH / 4;
    if (tid >= total4) return;

    int ch0 = ((int)(tid & 7)) * 4;
    float inv_n = 1.f / (float)n;

    float4 v = ((const float4*)h)[tid];
    float r[4] = {v.x, v.y, v.z, v.w};
#pragma unroll
    for (int j = 0; j < 4; ++j) {
        int ch = ch0 + j;
        float mean = stats[ch] * inv_n;
        float var = stats[NCH + ch] * inv_n - mean * mean;
        float scale = gamma[ch] * rsqrtf(var + 1e-5f);
        float shift = beta[ch] - mean * scale;
        float o = fmaf(r[j], scale, shift);
        r[j] = o > 0.f ? o : 0.f;
    }
    float4 o4;
    o4.x = r[0]; o4.y = r[1]; o4.z = r[2]; o4.w = r[3];
    ((float4*)h)[tid] = o4;
}

extern "C" void kernel_launch(void* const* d_in, const int* in_sizes, int n_in,
                              void* d_out, int out_size, void* d_ws, size_t ws_size,
                              hipStream_t stream)
{
    const float* feats = (const float*)d_in[0];
    const float* W1    = (const float*)d_in[1];
    const float* W2    = (const float*)d_in[2];
    const float* W3    = (const float*)d_in[3];
    const float* gamma = (const float*)d_in[4];
    const float* beta  = (const float*)d_in[5];
    const int*   nbr   = (const int*)d_in[6];   // [3 axes][3 taps][n]

    int n = in_sizes[0] / NCH;

    float*  hout = (float*)d_out;                     // h3, then final out
    ushort* h1   = (ushort*)d_ws;                     // n*32 bf16 (64 MB)
    ushort* h2   = h1 + (size_t)n * NCH;              // n*32 bf16 (64 MB)
    float*  stats = (float*)(h2 + (size_t)n * NCH);   // 64 floats

    const int cblocks = 1024;                    // round-2 grid, verified

    // conv1: axis 2 (z), fp32 feats -> bf16 h1
    conv_mfma_kernel<0, 1, 0><<<cblocks, 256, 0, stream>>>(
        feats, W1, nbr + (size_t)2 * 3 * n, h1, n, nullptr);
    // conv2: axis 1 (y), bf16 h1 -> bf16 h2
    conv_mfma_kernel<1, 1, 0><<<cblocks, 256, 0, stream>>>(
        h1, W2, nbr + (size_t)1 * 3 * n, h2, n, nullptr);

    // zero BN accumulators before conv3 (which fuses the stats reduction)
    hipMemsetAsync(stats, 0, 2 * NCH * sizeof(float), stream);

    // conv3: axis 0 (x), bf16 h2 -> fp32 h3 (d_out), fused sum/sumsq
    conv_mfma_kernel<1, 0, 1><<<cblocks, 256, 0, stream>>>(
        h2, W3, nbr + (size_t)0 * 3 * n, hout, n, stats);

    // BN + ReLU in place
    long total4 = (long)n * NCH / 4;
    int nblocks = (int)((total4 + 255) / 256);
    bn_relu_kernel<<<nblocks, 256, 0, stream>>>(hout, stats, gamma, beta, n);
}

// Round 8
// 410.363 us; speedup vs baseline: 1.5018x; 1.0105x over previous
//
#include <hip/hip_runtime.h>

#define NCH 32

typedef __attribute__((ext_vector_type(8))) __bf16 bf16x8;
typedef __attribute__((ext_vector_type(4))) float  f32x4;

union bcast16 { int4 i; bf16x8 h; };

// Split 8 fp32 values into bf16 hi + bf16 lo (residual) fragments.
// ah*bh + al*bh + ah*bl reconstructs the fp32 product to ~2^-16 relative.
static __device__ __forceinline__ void split8(const float* x, bf16x8& hi, bf16x8& lo)
{
#pragma unroll
    for (int e = 0; e < 8; ++e) {
        __bf16 h = (__bf16)x[e];
        hi[e] = h;
        lo[e] = (__bf16)(x[e] - (float)h);
    }
}

static __device__ __forceinline__ void mfma3(
    const bf16x8& ah, const bf16x8& al,
    const bf16x8& wh, const bf16x8& wl, f32x4& acc)
{
    acc = __builtin_amdgcn_mfma_f32_16x16x32_bf16(ah, wh, acc, 0, 0, 0);
    acc = __builtin_amdgcn_mfma_f32_16x16x32_bf16(al, wh, acc, 0, 0, 0);
    acc = __builtin_amdgcn_mfma_f32_16x16x32_bf16(ah, wl, acc, 0, 0, 0);
}

static __device__ __forceinline__ ushort f2bf(float x)
{
    __bf16 b = (__bf16)x;
    return *(const ushort*)&b;
}

// Factorized 1D sparse conv as MFMA GEMM over 16-point tiles — round-2
// structure verbatim; in/out dtypes templated.
// IN_BF16:  input rows are bf16 [n][32]; A fragment = one 16B load, no split.
// !IN_BF16: input rows are fp32; A split into bf16 hi/lo (exact to ~2^-16).
// OUT_BF16: store accumulators as bf16 (RNE); else fp32.
// ZERO_STATS: block 0 zeroes stats[64] at kernel start (consumed by the
// DO_STATS pass two kernel boundaries later -> ordering guaranteed).
// A fragment: lane holds f[row = tb + (lane&15)][c0..c0+7], c0=(lane>>4)*8.
// B fragments (3 taps x 2 halves, hi/lo = fp32-exact weights) in registers.
// C/D: out[tb + (lane>>4)*4 + r][(lane&15) + 16*half].
// Tap 1 is the identity map (offset 0) -> own row, no index load.
// Taps 0/2 behind wave-uniform __any skip (~37% whole-tile skip at 6% occ).
// DO_STATS: fused per-channel sum/sumsq from the fp32 accumulators,
// shuffle+LDS combine, 64 atomicAdds per block.
template<int IN_BF16, int OUT_BF16, int DO_STATS, int ZERO_STATS>
__global__ __launch_bounds__(256) void conv_mfma_kernel(
    const void* __restrict__ fin, const float* __restrict__ W,
    const int* __restrict__ idx, void* __restrict__ outv, int n,
    float* __restrict__ stats)
{
    __shared__ float red[4][4][16];

    if constexpr (ZERO_STATS) {
        if (blockIdx.x == 0 && threadIdx.x < 2 * NCH) stats[threadIdx.x] = 0.f;
    }

    const int lane = threadIdx.x & 63;
    const int wv   = threadIdx.x >> 6;
    const int r16  = lane & 15;
    const int g    = lane >> 4;
    const int c0   = g * 8;

    const float*  ff = (const float*)fin;
    const ushort* fb = (const ushort*)fin;
    float*  of = (float*)outv;
    ushort* ob = (ushort*)outv;

    // B fragments: 3 taps x 2 output halves, hi/lo split (held in VGPRs).
    bf16x8 bh[3][2], bl[3][2];
#pragma unroll
    for (int k = 0; k < 3; ++k) {
#pragma unroll
        for (int h = 0; h < 2; ++h) {
            float w8[8];
#pragma unroll
            for (int e = 0; e < 8; ++e)
                w8[e] = W[k * NCH * NCH + (c0 + e) * NCH + (h * 16 + r16)];
            split8(w8, bh[k][h], bl[k][h]);
        }
    }

    const int ntiles = (n + 15) >> 4;
    const int nw = gridDim.x * 4;
    float s0 = 0.f, q0 = 0.f, s1 = 0.f, q1 = 0.f;

    for (int tile = blockIdx.x * 4 + wv; tile < ntiles; tile += nw) {
        const int tb = tile << 4;
        f32x4 a0 = {0.f, 0.f, 0.f, 0.f};
        f32x4 a1 = {0.f, 0.f, 0.f, 0.f};

        const int  p   = tb + r16;
        const bool pin = (p < n);

        auto dotap = [&](int k, int row, bool v) {
            if constexpr (IN_BF16) {
                int4 raw = *(const int4*)(fb + (size_t)row * NCH + c0);
                if (!v) { raw.x = 0; raw.y = 0; raw.z = 0; raw.w = 0; }
                bcast16 u; u.i = raw;
                a0 = __builtin_amdgcn_mfma_f32_16x16x32_bf16(u.h, bh[k][0], a0, 0, 0, 0);
                a0 = __builtin_amdgcn_mfma_f32_16x16x32_bf16(u.h, bl[k][0], a0, 0, 0, 0);
                a1 = __builtin_amdgcn_mfma_f32_16x16x32_bf16(u.h, bh[k][1], a1, 0, 0, 0);
                a1 = __builtin_amdgcn_mfma_f32_16x16x32_bf16(u.h, bl[k][1], a1, 0, 0, 0);
            } else {
                const float4* rp = (const float4*)(ff + (size_t)row * NCH + c0);
                float4 x0 = rp[0];
                float4 x1 = rp[1];
                float m = v ? 1.f : 0.f;
                float x[8] = {x0.x * m, x0.y * m, x0.z * m, x0.w * m,
                              x1.x * m, x1.y * m, x1.z * m, x1.w * m};
                bf16x8 ah, al;
                split8(x, ah, al);
                mfma3(ah, al, bh[k][0], bl[k][0], a0);
                mfma3(ah, al, bh[k][1], bl[k][1], a1);
            }
        };

        // ---- tap 1: identity (own row) ----
        dotap(1, pin ? p : 0, pin);

        // ---- taps 0 and 2: random gathers ----
#pragma unroll
        for (int t = 0; t < 2; ++t) {
            const int k = t * 2;
            int  i = idx[(size_t)k * n + (pin ? p : 0)];
            bool v = pin && (i < n);
            if (__any(v)) dotap(k, v ? i : 0, v);
        }

        // ---- store C: row = tb + g*4 + r, col = r16 / r16+16 ----
#pragma unroll
        for (int r = 0; r < 4; ++r) {
            int prow = tb + g * 4 + r;
            if (prow < n) {
                if constexpr (OUT_BF16) {
                    ushort* o = ob + (size_t)prow * NCH + r16;
                    o[0]  = f2bf(a0[r]);
                    o[16] = f2bf(a1[r]);
                } else {
                    float* o = of + (size_t)prow * NCH + r16;
                    o[0]  = a0[r];
                    o[16] = a1[r];
                }
            }
        }

        if constexpr (DO_STATS) {
#pragma unroll
            for (int r = 0; r < 4; ++r) {
                s0 += a0[r]; q0 = fmaf(a0[r], a0[r], q0);
                s1 += a1[r]; q1 = fmaf(a1[r], a1[r], q1);
            }
        }
    }

    if constexpr (DO_STATS) {
        // lanes with the same (lane&15) hold the same channel: xor-16/32 reduce
        s0 += __shfl_xor(s0, 16); s0 += __shfl_xor(s0, 32);
        q0 += __shfl_xor(q0, 16); q0 += __shfl_xor(q0, 32);
        s1 += __shfl_xor(s1, 16); s1 += __shfl_xor(s1, 32);
        q1 += __shfl_xor(q1, 16); q1 += __shfl_xor(q1, 32);
        if (lane < 16) {
            red[wv][0][r16] = s0;
            red[wv][1][r16] = q0;
            red[wv][2][r16] = s1;
            red[wv][3][r16] = q1;
        }
        __syncthreads();
        if (threadIdx.x < 64) {
            int vsel = threadIdx.x >> 4;   // 0:sum lo, 1:sq lo, 2:sum hi, 3:sq hi
            int ch   = threadIdx.x & 15;
            float t = red[0][vsel][ch] + red[1][vsel][ch] +
                      red[2][vsel][ch] + red[3][vsel][ch];
            int channel = (vsel & 2) ? (ch + 16) : ch;
            atomicAdd(stats + ((vsel & 1) ? NCH : 0) + channel, t);
        }
    }
}

// BatchNorm (batch stats) + ReLU: read bf16 h3 [n,32], write fp32 out [n,32].
// One thread per 4 channels (8 B bf16 in, 16 B fp32 out).
__global__ __launch_bounds__(256) void bn_relu_kernel(
    const ushort* __restrict__ h3, float* __restrict__ out,
    const float* __restrict__ stats,
    const float* __restrict__ gamma, const float* __restrict__ beta, int n)
{
    long tid = (long)blockIdx.x * 256 + threadIdx.x;
    long total4 = (long)n * NCH / 4;
    if (tid >= total4) return;

    int ch0 = ((int)(tid & 7)) * 4;
    float inv_n = 1.f / (float)n;

    ushort4 v = ((const ushort4*)h3)[tid];
    ushort u[4] = {v.x, v.y, v.z, v.w};
    float r[4];
#pragma unroll
    for (int j = 0; j < 4; ++j)
        r[j] = __uint_as_float(((unsigned)u[j]) << 16);

#pragma unroll
    for (int j = 0; j < 4; ++j) {
        int ch = ch0 + j;
        float mean = stats[ch] * inv_n;
        float var = stats[NCH + ch] * inv_n - mean * mean;
        float scale = gamma[ch] * rsqrtf(var + 1e-5f);
        float shift = beta[ch] - mean * scale;
        float o = fmaf(r[j], scale, shift);
        r[j] = o > 0.f ? o : 0.f;
    }
    float4 o4;
    o4.x = r[0]; o4.y = r[1]; o4.z = r[2]; o4.w = r[3];
    ((float4*)out)[tid] = o4;
}

extern "C" void kernel_launch(void* const* d_in, const int* in_sizes, int n_in,
                              void* d_out, int out_size, void* d_ws, size_t ws_size,
                              hipStream_t stream)
{
    const float* feats = (const float*)d_in[0];
    const float* W1    = (const float*)d_in[1];
    const float* W2    = (const float*)d_in[2];
    const float* W3    = (const float*)d_in[3];
    const float* gamma = (const float*)d_in[4];
    const float* beta  = (const float*)d_in[5];
    const int*   nbr   = (const int*)d_in[6];   // [3 axes][3 taps][n]

    int n = in_sizes[0] / NCH;

    float*  hout = (float*)d_out;                     // final out (fp32)
    ushort* h1   = (ushort*)d_ws;                     // n*32 bf16; h3 reuses it
    ushort* h2   = h1 + (size_t)n * NCH;              // n*32 bf16
    ushort* h3   = h1;                                // h1 dead after conv2
    float*  stats = (float*)(h2 + (size_t)n * NCH);   // 64 floats

    // 2048 blocks x 4 waves = 8192 waves = full CU wave capacity at VGPR 44
    // (1024 was grid-capping occupancy at 50%; round-3's "more blocks"
    //  regression was confounded by a simultaneous loop restructure).
    const int cblocks = 2048;

    // conv1: axis 2 (z), fp32 feats -> bf16 h1; block 0 zeroes stats
    conv_mfma_kernel<0, 1, 0, 1><<<cblocks, 256, 0, stream>>>(
        feats, W1, nbr + (size_t)2 * 3 * n, h1, n, stats);
    // conv2: axis 1 (y), bf16 h1 -> bf16 h2
    conv_mfma_kernel<1, 1, 0, 0><<<cblocks, 256, 0, stream>>>(
        h1, W2, nbr + (size_t)1 * 3 * n, h2, n, stats);
    // conv3: axis 0 (x), bf16 h2 -> bf16 h3 (h1's slot), fused sum/sumsq
    conv_mfma_kernel<1, 1, 1, 0><<<cblocks, 256, 0, stream>>>(
        h2, W3, nbr + (size_t)0 * 3 * n, h3, n, stats);

    // BN + ReLU: bf16 h3 -> fp32 d_out
    long total4 = (long)n * NCH / 4;
    int nblocks = (int)((total4 + 255) / 256);
    bn_relu_kernel<<<nblocks, 256, 0, stream>>>(h3, hout, stats, gamma, beta, n);
}